// Round 1
// 589.313 us; speedup vs baseline: 1.0851x; 1.0851x over previous
//
#include <hip/hip_runtime.h>
#include <hip/hip_bf16.h>
#include <cstdint>
#include <cstddef>

// Problem: B=128, S=512, H=512, D=1024
// Outputs (flat in d_out): context (128*1024) | aw (128*512) | new_coverage (128*512)

typedef __attribute__((ext_vector_type(8))) short bf16x8;
typedef __attribute__((ext_vector_type(4))) float f32x4;

#define GLOBAL_AS(p) ((const __attribute__((address_space(1))) unsigned int*)(p))
#define LDS_AS(p)    ((__attribute__((address_space(3))) unsigned int*)(p))

__device__ __forceinline__ short f2bf(float f) {
    union { float f; uint32_t u; } v; v.f = f;
    uint32_t u = v.u + 0x7fffu + ((v.u >> 16) & 1u);  // RNE
    return (short)(u >> 16);
}

__device__ __forceinline__ float bf2f(short s) {
    union { uint32_t u; float f; } v; v.u = ((uint32_t)(uint16_t)s) << 16;
    return v.f;
}

__device__ __forceinline__ bf16x8 cvt8(float4 a, float4 b) {
    bf16x8 r;
    r[0] = f2bf(a.x); r[1] = f2bf(a.y); r[2] = f2bf(a.z); r[3] = f2bf(a.w);
    r[4] = f2bf(b.x); r[5] = f2bf(b.y); r[6] = f2bf(b.z); r[7] = f2bf(b.w);
    return r;
}

__device__ __forceinline__ float fast_tanh(float x) {
    x = fminf(10.f, fmaxf(-10.f, x));
    float e = __expf(2.f * x);
    return (e - 1.f) / (e + 1.f);
}

// tanh = 1 - 2/(e^{2x}+1); v_rcp instead of IEEE div (no fast-math in harness).
// e=inf -> rcp=0 -> +1; e=0 -> rcp(1)=1 -> -1: no clamp needed.
__device__ __forceinline__ float fast_tanh2(float x) {
    float e = __expf(2.f * x);
    return 1.f - 2.f * __builtin_amdgcn_rcpf(e + 1.f);
}

// ---------------- fused: fp32->bf16 cvt of [enc|Wh]  +  dec split-K GEMM -------
// blocks [0, 33280): cvt 8 elems/thread. blocks [33280, 33312): dec GEMM.
__global__ __launch_bounds__(256) void cvt_plus_dec(
    const float* __restrict__ enc, const float* __restrict__ Wh,
    short* __restrict__ enc_bf, short* __restrict__ Wh_bf,
    const float* __restrict__ hd, const float* __restrict__ cd,
    const float* __restrict__ Ws, float* __restrict__ dec_part)
{
    __shared__ __align__(16) short As[128 * 40];
    __shared__ __align__(16) short Bs[128 * 40];
    const int t = threadIdx.x;

    if (blockIdx.x < 33280) {
        size_t i = ((size_t)blockIdx.x * 256 + t) * 8;
        const float* src; short* dst; size_t off;
        const size_t NE = 67108864;   // 128*512*1024
        if (i < NE) { src = enc; dst = enc_bf; off = i; }
        else        { src = Wh;  dst = Wh_bf;  off = i - NE; }
        float4 a = *(const float4*)(src + off);
        float4 b = *(const float4*)(src + off + 4);
        *(bf16x8*)(dst + off) = cvt8(a, b);
        return;
    }

    // ---- dec GEMM: M=128, N=1024, K split 4x256 ----
    const int bid = blockIdx.x - 33280;
    const int bx = bid & 7;        // n-tile 0..7
    const int kc = bid >> 3;       // k-chunk 0..3
    const int wv = t >> 6, lane = t & 63, q = lane >> 4, c = lane & 15;
    const int wm = wv & 1, wn = wv >> 1;
    const int ar = t >> 1, ah = t & 1;

    const float* abase = ((kc < 2) ? hd : cd) + (size_t)ar * 512 + (kc & 1) * 256 + ah * 16;
    const float* bbase = Ws + ((size_t)(bx * 128 + ar)) * 1024 + kc * 256 + ah * 16;
    short* awr = &As[ar * 40 + ah * 16];
    short* bwr = &Bs[ar * 40 + ah * 16];

    f32x4 acc[4][4];
#pragma unroll
    for (int i = 0; i < 4; ++i)
#pragma unroll
        for (int j = 0; j < 4; ++j) acc[i][j] = (f32x4){0.f, 0.f, 0.f, 0.f};

    for (int k0 = 0; k0 < 256; k0 += 32) {
        const float4* ap = (const float4*)(abase + k0);
        const float4* bp = (const float4*)(bbase + k0);
        float4 a0 = ap[0], a1 = ap[1], a2 = ap[2], a3 = ap[3];
        float4 b0 = bp[0], b1 = bp[1], b2 = bp[2], b3 = bp[3];
        *(bf16x8*)awr = cvt8(a0, a1);
        *(bf16x8*)(awr + 8) = cvt8(a2, a3);
        *(bf16x8*)bwr = cvt8(b0, b1);
        *(bf16x8*)(bwr + 8) = cvt8(b2, b3);
        __syncthreads();
        bf16x8 af[4], bf[4];
#pragma unroll
        for (int i = 0; i < 4; ++i) af[i] = *(const bf16x8*)&As[(wm * 64 + i * 16 + c) * 40 + q * 8];
#pragma unroll
        for (int j = 0; j < 4; ++j) bf[j] = *(const bf16x8*)&Bs[(wn * 64 + j * 16 + c) * 40 + q * 8];
#pragma unroll
        for (int i = 0; i < 4; ++i)
#pragma unroll
            for (int j = 0; j < 4; ++j)
                acc[i][j] = __builtin_amdgcn_mfma_f32_16x16x32_bf16(af[i], bf[j], acc[i][j], 0, 0, 0);
        __syncthreads();
    }

    const int n0 = bx * 128 + wn * 64;
    float* dp = dec_part + (size_t)kc * 131072;
#pragma unroll
    for (int i = 0; i < 4; ++i)
#pragma unroll
        for (int rr = 0; rr < 4; ++rr) {
            int bidx = wm * 64 + i * 16 + q * 4 + rr;
#pragma unroll
            for (int j = 0; j < 4; ++j)
                dp[(size_t)bidx * 1024 + n0 + j * 16 + c] = acc[i][j][rr];
        }
}

// ---------------- main score GEMM: 8-phase counted-vmcnt schedule --------------
// M=65536, N=1024, K=1024. BM=BN=256, BK=64, 512 thr = 8 waves (2m x 4n),
// wave tile 128x64. LDS 128KB: [buf2][ks2][256][32] bf16 for A and B.
// 4 phases per k-tile: {ds_read (8 or 4) || 2 global_load_lds -> barrier ->
// lgkmcnt(0) -> setprio(1) 16 MFMA setprio(0) -> barrier}. vmcnt(4) once per
// k-tile (never 0 mid-loop): staging runs 1.5-2 tiles ahead at k-half
// granularity, into regions freed exactly one barrier earlier.
// Bank swizzle (rule #21): linear LDS dest, global source pre-XOR'd with
// slot ^= (row>>1)&3, same XOR on ds_read -> minimum 8 accesses/bank.

#define BARRIER() do { asm volatile("" ::: "memory"); \
    __builtin_amdgcn_s_barrier(); asm volatile("" ::: "memory"); } while (0)
#define WAIT_LGKM0() do { asm volatile("s_waitcnt lgkmcnt(0)" ::: "memory"); \
    __builtin_amdgcn_sched_barrier(0); } while (0)
#define STAGE(gp, kcol, arr, bufks, a) \
    __builtin_amdgcn_global_load_lds(GLOBAL_AS((gp) + (kcol)), \
        LDS_AS(&(arr)[(bufks) * 8192 + (a) * 4096 + wst]), 16, 0, 0)

__global__ __launch_bounds__(512, 2) void attn_score_gemm8(
    const short* __restrict__ encb, const short* __restrict__ Whb,
    const float* __restrict__ dec_part, const float* __restrict__ Wsb,
    const float* __restrict__ cov,
    const float* __restrict__ wc_w, const float* __restrict__ v_w,
    float* __restrict__ p_part)
{
    __shared__ __align__(16) short SA[32768];  // 64 KB: [buf2][ks2][256][32]
    __shared__ __align__(16) short SB[32768];  // 64 KB

    const int tid = threadIdx.x;
    const int wv = tid >> 6, lane = tid & 63, q = lane >> 4, c = lane & 15;
    const int wm = wv >> 2, wn = wv & 3;

    // XCD swizzle: 1024 blocks, round-robin dispatch -> xcd = lin&7.
    // Within an XCD the 4 n-tiles of one m-tile are consecutive (A-panel L2 hit).
    const int lin = blockIdx.x;
    const int xcd = lin & 7;
    const int idx = lin >> 3;            // 0..127
    const int bx  = idx & 3;             // n-tile 0..3
    const int my  = xcd * 32 + (idx >> 2);  // m-tile 0..255
    const int m0  = my * 256;
    const int n0  = bx * 256;
    const int b   = my >> 1;
    const int s0c = (my & 1) * 256;

    // staging: per-lane pre-swizzled global source (inverse of read swizzle)
    const int srow = tid >> 2;                              // 0..127
    const int SLOT = ((tid & 3) ^ ((tid >> 3) & 3)) * 8;    // shorts
    const short* gA0 = encb + (size_t)(m0 + srow) * 1024 + SLOT;
    const short* gA1 = gA0 + 131072;                        // +128 rows
    const short* gB0 = Whb + (size_t)(n0 + srow) * 1024 + SLOT;
    const short* gB1 = gB0 + 131072;
    const int wst = wv * 512;   // wave-uniform LDS stage base (wv*16 rows * 32)

    // fragment-read offsets with the same XOR swizzle
    const int sq = (q ^ ((c >> 1) & 3)) * 8;
    int aoff[8], boff[4];
#pragma unroll
    for (int i = 0; i < 8; ++i) aoff[i] = (wm * 128 + i * 16 + c) * 32 + sq;
#pragma unroll
    for (int j = 0; j < 4; ++j) boff[j] = (wn * 64 + j * 16 + c) * 32 + sq;

    f32x4 acc[8][4];
#pragma unroll
    for (int i = 0; i < 8; ++i)
#pragma unroll
        for (int j = 0; j < 4; ++j) acc[i][j] = (f32x4){0.f, 0.f, 0.f, 0.f};

    // ---- prologue: tile0 (both k-halves) + tile1 k-half0; keep t1 in flight ----
    STAGE(gA0,  0, SA, 0, 0);  STAGE(gA1,  0, SA, 0, 1);
    STAGE(gB0,  0, SB, 0, 0);  STAGE(gB1,  0, SB, 0, 1);
    STAGE(gA0, 32, SA, 1, 0);  STAGE(gA1, 32, SA, 1, 1);
    STAGE(gB0, 32, SB, 1, 0);  STAGE(gB1, 32, SB, 1, 1);
    STAGE(gA0, 64, SA, 2, 0);  STAGE(gA1, 64, SA, 2, 1);
    STAGE(gB0, 64, SB, 2, 0);  STAGE(gB1, 64, SB, 2, 1);
    asm volatile("s_waitcnt vmcnt(4)" ::: "memory");   // t0 resident, t1-kh0 flying
    __builtin_amdgcn_s_barrier();
    asm volatile("" ::: "memory");

#pragma unroll 2
    for (int t = 0; t < 16; ++t) {
        const int cur = t & 1, nxt = cur ^ 1;
        const int kc = t * 64;
        const short* A0 = &SA[cur * 16384];
        const short* A1 = A0 + 8192;
        const short* B0 = &SB[cur * 16384];
        const short* B1 = B0 + 8192;

        bf16x8 af[4], bfr[4];

        // ---- phase 1: ks0 x mh0 (8 ds_read; stage A-kh1 of t+1 -> buf nxt) ----
#pragma unroll
        for (int i = 0; i < 4; ++i) af[i] = *(const bf16x8*)&A0[aoff[i]];
#pragma unroll
        for (int j = 0; j < 4; ++j) bfr[j] = *(const bf16x8*)&B0[boff[j]];
        if (t < 15) { STAGE(gA0, kc + 96, SA, nxt * 2 + 1, 0);
                      STAGE(gA1, kc + 96, SA, nxt * 2 + 1, 1); }
        BARRIER();
        WAIT_LGKM0();
        __builtin_amdgcn_s_setprio(1);
#pragma unroll
        for (int i = 0; i < 4; ++i)
#pragma unroll
            for (int j = 0; j < 4; ++j)
                acc[i][j] = __builtin_amdgcn_mfma_f32_16x16x32_bf16(af[i], bfr[j], acc[i][j], 0, 0, 0);
        __builtin_amdgcn_s_setprio(0);
        BARRIER();

        // ---- phase 2: ks0 x mh1 (4 ds_read, bfr reused; stage B-kh1 of t+1) ----
#pragma unroll
        for (int i = 0; i < 4; ++i) af[i] = *(const bf16x8*)&A0[aoff[4 + i]];
        if (t < 15) { STAGE(gB0, kc + 96, SB, nxt * 2 + 1, 0);
                      STAGE(gB1, kc + 96, SB, nxt * 2 + 1, 1); }
        BARRIER();
        WAIT_LGKM0();
        __builtin_amdgcn_s_setprio(1);
#pragma unroll
        for (int i = 0; i < 4; ++i)
#pragma unroll
            for (int j = 0; j < 4; ++j)
                acc[4 + i][j] = __builtin_amdgcn_mfma_f32_16x16x32_bf16(af[i], bfr[j], acc[4 + i][j], 0, 0, 0);
        __builtin_amdgcn_s_setprio(0);
        BARRIER();

        // ---- phase 3: ks1 x mh0 (8 ds_read; stage A-kh0 of t+2 -> buf cur,
        //      region freed at phase 2's barrier) ----
#pragma unroll
        for (int i = 0; i < 4; ++i) af[i] = *(const bf16x8*)&A1[aoff[i]];
#pragma unroll
        for (int j = 0; j < 4; ++j) bfr[j] = *(const bf16x8*)&B1[boff[j]];
        if (t < 14) { STAGE(gA0, kc + 128, SA, cur * 2, 0);
                      STAGE(gA1, kc + 128, SA, cur * 2, 1); }
        BARRIER();
        WAIT_LGKM0();
        __builtin_amdgcn_s_setprio(1);
#pragma unroll
        for (int i = 0; i < 4; ++i)
#pragma unroll
            for (int j = 0; j < 4; ++j)
                acc[i][j] = __builtin_amdgcn_mfma_f32_16x16x32_bf16(af[i], bfr[j], acc[i][j], 0, 0, 0);
        __builtin_amdgcn_s_setprio(0);
        BARRIER();

        // ---- phase 4: ks1 x mh1 (4 ds_read; stage B-kh0 of t+2) ----
#pragma unroll
        for (int i = 0; i < 4; ++i) af[i] = *(const bf16x8*)&A1[aoff[4 + i]];
        if (t < 14) { STAGE(gB0, kc + 128, SB, cur * 2, 0);
                      STAGE(gB1, kc + 128, SB, cur * 2, 1); }
        BARRIER();
        WAIT_LGKM0();
        __builtin_amdgcn_s_setprio(1);
#pragma unroll
        for (int i = 0; i < 4; ++i)
#pragma unroll
            for (int j = 0; j < 4; ++j)
                acc[4 + i][j] = __builtin_amdgcn_mfma_f32_16x16x32_bf16(af[i], bfr[j], acc[4 + i][j], 0, 0, 0);
        __builtin_amdgcn_s_setprio(0);
        // k-tile boundary: t+1's data must be resident. Newest 4 loads
        // (t+2's kh0, issued in phases 3/4) may stay in flight.
        if (t <= 13) asm volatile("s_waitcnt vmcnt(4)" ::: "memory");
        else         asm volatile("s_waitcnt vmcnt(0)" ::: "memory");
        __builtin_amdgcn_s_barrier();
        asm volatile("" ::: "memory");
    }

    // ---- epilogue: p = sum over this wave's 64 e of v[e]*tanh(acc+dec+cov*wc) ----
    const int eb = n0 + wn * 64;
    float v_e[4], wc_e[4], dec_e[4];
#pragma unroll
    for (int j = 0; j < 4; ++j) {
        int e = eb + j * 16 + c;
        v_e[j]  = v_w[e];
        wc_e[j] = wc_w[e];
        float d = Wsb[e];
#pragma unroll
        for (int p = 0; p < 4; ++p) d += dec_part[(size_t)p * 131072 + (size_t)b * 1024 + e];
        dec_e[j] = d;
    }
    const float* covb = cov + (size_t)b * 512 + s0c;
    float* pp = p_part + (size_t)(bx * 4 + wn) * 65536 + (size_t)my * 256;
#pragma unroll
    for (int i = 0; i < 8; ++i)
#pragma unroll
        for (int rr = 0; rr < 4; ++rr) {
            int r = wm * 128 + i * 16 + q * 4 + rr;
            float cs = covb[r];
            float p = 0.f;
#pragma unroll
            for (int j = 0; j < 4; ++j) {
                float att = acc[i][j][rr] + dec_e[j] + cs * wc_e[j];
                p += v_e[j] * fast_tanh2(att);
            }
            p += __shfl_xor(p, 1);
            p += __shfl_xor(p, 2);
            p += __shfl_xor(p, 4);
            p += __shfl_xor(p, 8);
            if (c == 0) pp[r] = p;
        }
}

// ---------------- fallback score GEMM (fp32 A, register cvt, 16 slices) --------
__global__ __launch_bounds__(256) void attn_score_gemm_fb(
    const float* __restrict__ enc, const short* __restrict__ Wh,
    const float* __restrict__ dec_feat, const float* __restrict__ cov,
    const float* __restrict__ wc_w, const float* __restrict__ v_w,
    float* __restrict__ p_part)
{
    __shared__ __align__(16) short As[128 * 40];
    __shared__ __align__(16) short Bs[128 * 40];
    const int t = threadIdx.x;
    const int bx = blockIdx.x;
    const int by = blockIdx.y;
    const int b  = by >> 2;
    const int s0 = (by & 3) * 128;

    const int wv = t >> 6, lane = t & 63, q = lane >> 4, c = lane & 15;
    const int wm = wv & 1, wn = wv >> 1;
    const int ar = t >> 1, ah = t & 1;

    const float* aptr = enc + ((size_t)(by * 128 + ar)) * 1024 + ah * 16;
    const short* bptr = Wh + ((size_t)(bx * 128 + ar)) * 1024 + ah * 16;
    short* awr = &As[ar * 40 + ah * 16];
    short* bwr = &Bs[ar * 40 + ah * 16];

    f32x4 acc[4][4];
#pragma unroll
    for (int i = 0; i < 4; ++i)
#pragma unroll
        for (int j = 0; j < 4; ++j) acc[i][j] = (f32x4){0.f, 0.f, 0.f, 0.f};

    for (int k0 = 0; k0 < 1024; k0 += 32) {
        const float4* ap = (const float4*)(aptr + k0);
        float4 a0 = ap[0], a1 = ap[1], a2 = ap[2], a3 = ap[3];
        bf16x8 bv0 = *(const bf16x8*)(bptr + k0);
        bf16x8 bv1 = *(const bf16x8*)(bptr + k0 + 8);
        *(bf16x8*)awr = cvt8(a0, a1);
        *(bf16x8*)(awr + 8) = cvt8(a2, a3);
        *(bf16x8*)bwr = bv0;
        *(bf16x8*)(bwr + 8) = bv1;
        __syncthreads();
        bf16x8 af[4], bf[4];
#pragma unroll
        for (int i = 0; i < 4; ++i) af[i] = *(const bf16x8*)&As[(wm * 64 + i * 16 + c) * 40 + q * 8];
#pragma unroll
        for (int j = 0; j < 4; ++j) bf[j] = *(const bf16x8*)&Bs[(wn * 64 + j * 16 + c) * 40 + q * 8];
#pragma unroll
        for (int i = 0; i < 4; ++i)
#pragma unroll
            for (int j = 0; j < 4; ++j)
                acc[i][j] = __builtin_amdgcn_mfma_f32_16x16x32_bf16(af[i], bf[j], acc[i][j], 0, 0, 0);
        __syncthreads();
    }

    const int n0 = bx * 128 + wn * 64;
    float v_e[4], wc_e[4], dec_e[4];
#pragma unroll
    for (int j = 0; j < 4; ++j) {
        int e = n0 + j * 16 + c;
        v_e[j]  = v_w[e];
        wc_e[j] = wc_w[e];
        dec_e[j] = dec_feat[(size_t)b * 1024 + e];
    }
    const float* covb = cov + (size_t)b * 512;
    float* pp = p_part + ((size_t)(bx * 2 + wn)) * 65536 + (size_t)b * 512;
#pragma unroll
    for (int i = 0; i < 4; ++i)
#pragma unroll
        for (int rr = 0; rr < 4; ++rr) {
            int s = s0 + wm * 64 + i * 16 + q * 4 + rr;
            float cs = covb[s];
            float p = 0.f;
#pragma unroll
            for (int j = 0; j < 4; ++j) {
                float att = acc[i][j][rr] + dec_e[j] + cs * wc_e[j];
                p += v_e[j] * fast_tanh(att);
            }
            p += __shfl_xor(p, 1);
            p += __shfl_xor(p, 2);
            p += __shfl_xor(p, 4);
            p += __shfl_xor(p, 8);
            if (c == 0) pp[s] = p;
        }
}

// fallback dec gemm (bf16 Ws, full K, with bias)
__global__ __launch_bounds__(256) void dec_gemm(
    const float* __restrict__ hd, const float* __restrict__ cd,
    const short* __restrict__ Ws, const float* __restrict__ Wsb,
    float* __restrict__ dec_feat)
{
    __shared__ __align__(16) short As[128 * 40];
    __shared__ __align__(16) short Bs[128 * 40];
    const int t = threadIdx.x;
    const int bx = blockIdx.x;
    const int wv = t >> 6, lane = t & 63, q = lane >> 4, c = lane & 15;
    const int wm = wv & 1, wn = wv >> 1;
    const int ar = t >> 1, ah = t & 1;

    const short* bptr = Ws + ((size_t)(bx * 128 + ar)) * 1024 + ah * 16;
    short* awr = &As[ar * 40 + ah * 16];
    short* bwr = &Bs[ar * 40 + ah * 16];

    f32x4 acc[4][4];
#pragma unroll
    for (int i = 0; i < 4; ++i)
#pragma unroll
        for (int j = 0; j < 4; ++j) acc[i][j] = (f32x4){0.f, 0.f, 0.f, 0.f};

    for (int k0 = 0; k0 < 1024; k0 += 32) {
        const int k = k0 + ah * 16;
        const float* src = (k < 512) ? (hd + (size_t)ar * 512 + k)
                                     : (cd + (size_t)ar * 512 + (k - 512));
        const float4* ap = (const float4*)src;
        float4 a0 = ap[0], a1 = ap[1], a2 = ap[2], a3 = ap[3];
        bf16x8 bv0 = *(const bf16x8*)(bptr + k0);
        bf16x8 bv1 = *(const bf16x8*)(bptr + k0 + 8);
        *(bf16x8*)awr = cvt8(a0, a1);
        *(bf16x8*)(awr + 8) = cvt8(a2, a3);
        *(bf16x8*)bwr = bv0;
        *(bf16x8*)(bwr + 8) = bv1;
        __syncthreads();
        bf16x8 af[4], bf[4];
#pragma unroll
        for (int i = 0; i < 4; ++i) af[i] = *(const bf16x8*)&As[(wm * 64 + i * 16 + c) * 40 + q * 8];
#pragma unroll
        for (int j = 0; j < 4; ++j) bf[j] = *(const bf16x8*)&Bs[(wn * 64 + j * 16 + c) * 40 + q * 8];
#pragma unroll
        for (int i = 0; i < 4; ++i)
#pragma unroll
            for (int j = 0; j < 4; ++j)
                acc[i][j] = __builtin_amdgcn_mfma_f32_16x16x32_bf16(af[i], bf[j], acc[i][j], 0, 0, 0);
        __syncthreads();
    }

    const int n0 = bx * 128 + wn * 64;
    float wsb_e[4];
#pragma unroll
    for (int j = 0; j < 4; ++j) wsb_e[j] = Wsb[n0 + j * 16 + c];
#pragma unroll
    for (int i = 0; i < 4; ++i)
#pragma unroll
        for (int rr = 0; rr < 4; ++rr) {
            int bidx = wm * 64 + i * 16 + q * 4 + rr;
#pragma unroll
            for (int j = 0; j < 4; ++j) {
                int e = n0 + j * 16 + c;
                dec_feat[(size_t)bidx * 1024 + e] = acc[i][j][rr] + wsb_e[j];
            }
        }
}

// ---------------- softmax: sum ns partials, masked softmax + renorm ------------
__global__ __launch_bounds__(512) void softmax_kernel(
    const float* __restrict__ p_part, int ns, const float* __restrict__ mask,
    const float* __restrict__ cov, float* __restrict__ aw, float* __restrict__ ncov)
{
    __shared__ float red[8];
    const int b = blockIdx.x, t = threadIdx.x;
    const int w = t >> 6, lane = t & 63;
    const size_t idx = (size_t)b * 512 + t;

    float sc = 0.f;
    for (int k = 0; k < ns; ++k) sc += p_part[(size_t)k * 65536 + idx];

    float m = sc;
#pragma unroll
    for (int o = 1; o < 64; o <<= 1) m = fmaxf(m, __shfl_xor(m, o));
    if (lane == 0) red[w] = m;
    __syncthreads();
#pragma unroll
    for (int i = 0; i < 8; ++i) m = fmaxf(m, red[i]);
    __syncthreads();

    float e = __expf(sc - m);
    float s = e;
#pragma unroll
    for (int o = 1; o < 64; o <<= 1) s += __shfl_xor(s, o);
    if (lane == 0) red[w] = s;
    __syncthreads();
    s = 0.f;
#pragma unroll
    for (int i = 0; i < 8; ++i) s += red[i];
    __syncthreads();

    float wv = (e / s) * mask[idx];
    float s2 = wv;
#pragma unroll
    for (int o = 1; o < 64; o <<= 1) s2 += __shfl_xor(s2, o);
    if (lane == 0) red[w] = s2;
    __syncthreads();
    s2 = 0.f;
#pragma unroll
    for (int i = 0; i < 8; ++i) s2 += red[i];

    float awv = wv / s2;
    aw[idx] = awv;
    ncov[idx] = cov[idx] + awv;
}

// ---------------- context: partial-sum (no atomics) + reduce -------------------
__global__ __launch_bounds__(256) void context_part(
    const short* __restrict__ encb, const float* __restrict__ aw, float* __restrict__ cpart)
{
    const int sc = blockIdx.x & 7;     // s-chunk of 64
    const int b  = blockIdx.x >> 3;    // 0..127
    const int t  = threadIdx.x;
    const int dl = t & 127;
    const int si = t >> 7;
    const short* ebase = encb + ((size_t)(b * 512 + sc * 64 + si)) * 1024 + dl * 8;
    const float* awp = aw + (size_t)b * 512 + sc * 64 + si;
    float acc[8];
#pragma unroll
    for (int i = 0; i < 8; ++i) acc[i] = 0.f;
#pragma unroll 16
    for (int s = 0; s < 64; s += 2) {
        float w = awp[s];
        bf16x8 e = *(const bf16x8*)(ebase + (size_t)s * 1024);
#pragma unroll
        for (int i = 0; i < 8; ++i) acc[i] += w * bf2f(e[i]);
    }
    float* cp = cpart + ((size_t)(sc * 2 + si) * 128 + b) * 1024 + dl * 8;
    *(float4*)(cp)     = (float4){acc[0], acc[1], acc[2], acc[3]};
    *(float4*)(cp + 4) = (float4){acc[4], acc[5], acc[6], acc[7]};
}

__global__ __launch_bounds__(256) void ctx_reduce(
    const float* __restrict__ cpart, float* __restrict__ ctx)
{
    int i = blockIdx.x * 256 + threadIdx.x;
    float s = 0.f;
#pragma unroll
    for (int k = 0; k < 16; ++k) s += cpart[(size_t)k * 131072 + i];
    ctx[i] = s;
}

// fp32 fallback context
__global__ __launch_bounds__(256) void context_f32(
    const float* __restrict__ enc, const float* __restrict__ aw, float* __restrict__ ctx)
{
    const int schunk = blockIdx.x;
    const int b = blockIdx.y;
    const int t = threadIdx.x;
    const float* ebase = enc + ((size_t)(b * 512 + schunk * 128)) * 1024 + t * 4;
    const float* awp = aw + (size_t)b * 512 + schunk * 128;
    float ax = 0.f, ay = 0.f, az = 0.f, aww = 0.f;
#pragma unroll 4
    for (int s = 0; s < 128; ++s) {
        float w = awp[s];
        float4 e4 = *(const float4*)(ebase + (size_t)s * 1024);
        ax += w * e4.x; ay += w * e4.y; az += w * e4.z; aww += w * e4.w;
    }
    float* cp = ctx + (size_t)b * 1024 + t * 4;
    atomicAdd(cp + 0, ax);
    atomicAdd(cp + 1, ay);
    atomicAdd(cp + 2, az);
    atomicAdd(cp + 3, aww);
}

// small cvt for fallback path (weights only)
__global__ void cvt_f32_bf16(const float* __restrict__ src, short* __restrict__ dst, int n) {
    int i = (blockIdx.x * 256 + threadIdx.x) * 4;
    if (i < n) {
        float4 f = *(const float4*)(src + i);
        short4 o;
        o.x = f2bf(f.x); o.y = f2bf(f.y); o.z = f2bf(f.z); o.w = f2bf(f.w);
        *(short4*)(dst + i) = o;
    }
}

extern "C" void kernel_launch(void* const* d_in, const int* in_sizes, int n_in,
                              void* d_out, int out_size, void* d_ws, size_t ws_size,
                              hipStream_t stream) {
    const float* hd   = (const float*)d_in[0];
    const float* cd   = (const float*)d_in[1];
    const float* enc  = (const float*)d_in[2];
    const float* mask = (const float*)d_in[3];
    const float* cov  = (const float*)d_in[4];
    const float* Wh   = (const float*)d_in[5];
    const float* Ws   = (const float*)d_in[6];
    const float* Wsb  = (const float*)d_in[7];
    const float* vw   = (const float*)d_in[8];
    const float* wcw  = (const float*)d_in[9];

    float* out  = (float*)d_out;
    float* ctx  = out;
    float* aw   = out + 131072;
    float* ncov = out + 196608;

    // ws layout (big path): p_part 4MB | dec_part 2MB | Wh_bf 2MB | enc_bf 128MB
    // cpart (8MB) overlays [0..8MB) — all dead by context time.
    char* ws = (char*)d_ws;
    float* p_part   = (float*)ws;
    float* dec_part = (float*)(ws + (4u << 20));
    short* Wh_bf    = (short*)(ws + (6u << 20));
    short* enc_bf   = (short*)(ws + (8u << 20));
    float* cpart    = (float*)ws;
    const size_t need_big = (8ull << 20) + (128ull << 20);

    if (ws_size >= need_big) {
        cvt_plus_dec<<<33312, 256, 0, stream>>>(enc, Wh, enc_bf, Wh_bf, hd, cd, Ws, dec_part);
        attn_score_gemm8<<<1024, 512, 0, stream>>>(enc_bf, Wh_bf, dec_part, Wsb, cov, wcw, vw, p_part);
        softmax_kernel<<<128, 512, 0, stream>>>(p_part, 16, mask, cov, aw, ncov);
        context_part<<<1024, 256, 0, stream>>>(enc_bf, aw, cpart);
        ctx_reduce<<<512, 256, 0, stream>>>(cpart, ctx);
    } else {
        // fallback layout: p_part 4MB | dec_feat 512KB | Wh_bf 2MB | Ws_bf 2MB
        float* p_part16 = (float*)ws;
        float* dec_feat = (float*)(ws + (4u << 20));
        short* Wh_bf2   = (short*)(ws + (4u << 20) + (512u << 10));
        short* Ws_bf    = (short*)(ws + (6u << 20) + (512u << 10));
        hipMemsetAsync(ctx, 0, 128 * 1024 * sizeof(float), stream);
        cvt_f32_bf16<<<1024, 256, 0, stream>>>(Wh, Wh_bf2, 1024 * 1024);
        cvt_f32_bf16<<<1024, 256, 0, stream>>>(Ws, Ws_bf, 1024 * 1024);
        dec_gemm<<<8, 256, 0, stream>>>(hd, cd, Ws_bf, Wsb, dec_feat);
        attn_score_gemm_fb<<<dim3(8, 512), 256, 0, stream>>>(enc, Wh_bf2, dec_feat, cov, wcw, vw, p_part16);
        softmax_kernel<<<128, 512, 0, stream>>>(p_part16, 16, mask, cov, aw, ncov);
        context_f32<<<dim3(4, 128), 256, 0, stream>>>(enc, aw, ctx);
    }
}

// Round 3
// 583.474 us; speedup vs baseline: 1.0960x; 1.0100x over previous
//
#include <hip/hip_runtime.h>
#include <hip/hip_bf16.h>
#include <cstdint>
#include <cstddef>

// Problem: B=128, S=512, H=512, D=1024
// Outputs (flat in d_out): context (128*1024) | aw (128*512) | new_coverage (128*512)

typedef __attribute__((ext_vector_type(8))) short bf16x8;
typedef __attribute__((ext_vector_type(4))) float f32x4;

#define GLOBAL_AS(p) ((const __attribute__((address_space(1))) unsigned int*)(p))
#define LDS_AS(p)    ((__attribute__((address_space(3))) unsigned int*)(p))

__device__ __forceinline__ short f2bf(float f) {
    union { float f; uint32_t u; } v; v.f = f;
    uint32_t u = v.u + 0x7fffu + ((v.u >> 16) & 1u);  // RNE
    return (short)(u >> 16);
}

__device__ __forceinline__ float bf2f(short s) {
    union { uint32_t u; float f; } v; v.u = ((uint32_t)(uint16_t)s) << 16;
    return v.f;
}

__device__ __forceinline__ bf16x8 cvt8(float4 a, float4 b) {
    bf16x8 r;
    r[0] = f2bf(a.x); r[1] = f2bf(a.y); r[2] = f2bf(a.z); r[3] = f2bf(a.w);
    r[4] = f2bf(b.x); r[5] = f2bf(b.y); r[6] = f2bf(b.z); r[7] = f2bf(b.w);
    return r;
}

__device__ __forceinline__ float fast_tanh(float x) {
    x = fminf(10.f, fmaxf(-10.f, x));
    float e = __expf(2.f * x);
    return (e - 1.f) / (e + 1.f);
}

// tanh = 1 - 2/(2^{x*2*log2e}+1); v_exp + v_rcp, no IEEE div, no clamp needed:
// x->+inf: exp2=inf -> rcp=0 -> +1; x->-inf: exp2=0 -> rcp(1)=1 -> -1.
__device__ __forceinline__ float fast_tanh2(float x) {
    float e = __builtin_amdgcn_exp2f(x * 2.885390081777927f);
    return 1.f - 2.f * __builtin_amdgcn_rcpf(e + 1.f);
}

// ---------------- fused: fp32->bf16 cvt of [enc|Wh]  +  dec split-K GEMM -------
// blocks [0, 33280): cvt 8 elems/thread. blocks [33280, 33312): dec GEMM.
__global__ __launch_bounds__(256) void cvt_plus_dec(
    const float* __restrict__ enc, const float* __restrict__ Wh,
    short* __restrict__ enc_bf, short* __restrict__ Wh_bf,
    const float* __restrict__ hd, const float* __restrict__ cd,
    const float* __restrict__ Ws, float* __restrict__ dec_part)
{
    __shared__ __align__(16) short As[128 * 40];
    __shared__ __align__(16) short Bs[128 * 40];
    const int t = threadIdx.x;

    if (blockIdx.x < 33280) {
        size_t i = ((size_t)blockIdx.x * 256 + t) * 8;
        const float* src; short* dst; size_t off;
        const size_t NE = 67108864;   // 128*512*1024
        if (i < NE) { src = enc; dst = enc_bf; off = i; }
        else        { src = Wh;  dst = Wh_bf;  off = i - NE; }
        float4 a = *(const float4*)(src + off);
        float4 b = *(const float4*)(src + off + 4);
        *(bf16x8*)(dst + off) = cvt8(a, b);
        return;
    }

    // ---- dec GEMM: M=128, N=1024, K split 4x256 ----
    const int bid = blockIdx.x - 33280;
    const int bx = bid & 7;        // n-tile 0..7
    const int kc = bid >> 3;       // k-chunk 0..3
    const int wv = t >> 6, lane = t & 63, q = lane >> 4, c = lane & 15;
    const int wm = wv & 1, wn = wv >> 1;
    const int ar = t >> 1, ah = t & 1;

    const float* abase = ((kc < 2) ? hd : cd) + (size_t)ar * 512 + (kc & 1) * 256 + ah * 16;
    const float* bbase = Ws + ((size_t)(bx * 128 + ar)) * 1024 + kc * 256 + ah * 16;
    short* awr = &As[ar * 40 + ah * 16];
    short* bwr = &Bs[ar * 40 + ah * 16];

    f32x4 acc[4][4];
#pragma unroll
    for (int i = 0; i < 4; ++i)
#pragma unroll
        for (int j = 0; j < 4; ++j) acc[i][j] = (f32x4){0.f, 0.f, 0.f, 0.f};

    for (int k0 = 0; k0 < 256; k0 += 32) {
        const float4* ap = (const float4*)(abase + k0);
        const float4* bp = (const float4*)(bbase + k0);
        float4 a0 = ap[0], a1 = ap[1], a2 = ap[2], a3 = ap[3];
        float4 b0 = bp[0], b1 = bp[1], b2 = bp[2], b3 = bp[3];
        *(bf16x8*)awr = cvt8(a0, a1);
        *(bf16x8*)(awr + 8) = cvt8(a2, a3);
        *(bf16x8*)bwr = cvt8(b0, b1);
        *(bf16x8*)(bwr + 8) = cvt8(b2, b3);
        __syncthreads();
        bf16x8 af[4], bf[4];
#pragma unroll
        for (int i = 0; i < 4; ++i) af[i] = *(const bf16x8*)&As[(wm * 64 + i * 16 + c) * 40 + q * 8];
#pragma unroll
        for (int j = 0; j < 4; ++j) bf[j] = *(const bf16x8*)&Bs[(wn * 64 + j * 16 + c) * 40 + q * 8];
#pragma unroll
        for (int i = 0; i < 4; ++i)
#pragma unroll
            for (int j = 0; j < 4; ++j)
                acc[i][j] = __builtin_amdgcn_mfma_f32_16x16x32_bf16(af[i], bf[j], acc[i][j], 0, 0, 0);
        __syncthreads();
    }

    const int n0 = bx * 128 + wn * 64;
    float* dp = dec_part + (size_t)kc * 131072;
#pragma unroll
    for (int i = 0; i < 4; ++i)
#pragma unroll
        for (int rr = 0; rr < 4; ++rr) {
            int bidx = wm * 64 + i * 16 + q * 4 + rr;
#pragma unroll
            for (int j = 0; j < 4; ++j)
                dp[(size_t)bidx * 1024 + n0 + j * 16 + c] = acc[i][j][rr];
        }
}

// ---------------- main score GEMM: minimal-barrier counted-vmcnt schedule ------
// M=65536, N=1024, K=1024. BM=BN=256, BK=64, 512 thr = 8 waves (2m x 4n),
// wave tile 128x64. LDS 128KB: [buf2][ks2][256][32] bf16 for A and B.
// Per k-tile: 4 MFMA clusters of 16, but only TWO barriers:
//   #1 after kh0 MFMAs (all waves' kh0 reads complete -> stages into cur-kh0
//      in P3/P4 are safe), and #2 at the tile boundary (vmcnt(4) + barrier:
//      staged data for t+1 resident; all kh1 reads complete before t+1's
//      stages into cur-kh1). Reads of STABLE regions need no barrier, so each
//      wave issues its next ds_reads right after its MFMA cluster issues —
//      wave skew overlaps one wave's LDS drain with another's MFMA.
// vmcnt never drains to 0 mid-loop (T4). Bank swizzle per rule #21 (verified
// 0 conflicts in R1).

#define BARRIER() do { asm volatile("" ::: "memory"); \
    __builtin_amdgcn_s_barrier(); asm volatile("" ::: "memory"); } while (0)
#define WAIT_LGKM0() do { asm volatile("s_waitcnt lgkmcnt(0)" ::: "memory"); \
    __builtin_amdgcn_sched_barrier(0); } while (0)
#define STAGE(gp, kcol, arr, bufks, a) \
    __builtin_amdgcn_global_load_lds(GLOBAL_AS((gp) + (kcol)), \
        LDS_AS(&(arr)[(bufks) * 8192 + (a) * 4096 + wst]), 16, 0, 0)

__global__ __launch_bounds__(512, 2) void attn_score_gemm8(
    const short* __restrict__ encb, const short* __restrict__ Whb,
    const float* __restrict__ dec_part, const float* __restrict__ Wsb,
    const float* __restrict__ cov,
    const float* __restrict__ wc_w, const float* __restrict__ v_w,
    float* __restrict__ p_part)
{
    __shared__ __align__(16) short SA[32768];  // 64 KB: [buf2][ks2][256][32]
    __shared__ __align__(16) short SB[32768];  // 64 KB

    const int tid = threadIdx.x;
    const int wv = tid >> 6, lane = tid & 63, q = lane >> 4, c = lane & 15;
    const int wm = wv >> 2, wn = wv & 3;

    // XCD swizzle: 1024 blocks, round-robin dispatch -> xcd = lin&7.
    const int lin = blockIdx.x;
    const int xcd = lin & 7;
    const int idx = lin >> 3;            // 0..127
    const int bx  = idx & 3;             // n-tile 0..3
    const int my  = xcd * 32 + (idx >> 2);  // m-tile 0..255
    const int m0  = my * 256;
    const int n0  = bx * 256;
    const int b   = my >> 1;
    const int s0c = (my & 1) * 256;

    // staging: per-lane pre-swizzled global source (inverse of read swizzle)
    const int srow = tid >> 2;                              // 0..127
    const int SLOT = ((tid & 3) ^ ((tid >> 3) & 3)) * 8;    // shorts
    const short* gA0 = encb + (size_t)(m0 + srow) * 1024 + SLOT;
    const short* gA1 = gA0 + 131072;                        // +128 rows
    const short* gB0 = Whb + (size_t)(n0 + srow) * 1024 + SLOT;
    const short* gB1 = gB0 + 131072;
    const int wst = wv * 512;   // wave-uniform LDS stage base (wv*16 rows * 32)

    // fragment-read offsets with the same XOR swizzle
    const int sq = (q ^ ((c >> 1) & 3)) * 8;
    int aoff[8], boff[4];
#pragma unroll
    for (int i = 0; i < 8; ++i) aoff[i] = (wm * 128 + i * 16 + c) * 32 + sq;
#pragma unroll
    for (int j = 0; j < 4; ++j) boff[j] = (wn * 64 + j * 16 + c) * 32 + sq;

    f32x4 acc[8][4];
#pragma unroll
    for (int i = 0; i < 8; ++i)
#pragma unroll
        for (int j = 0; j < 4; ++j) acc[i][j] = (f32x4){0.f, 0.f, 0.f, 0.f};

    // ---- prologue: tile0 (both k-halves) + tile1 k-half0; keep t1 in flight ----
    STAGE(gA0,  0, SA, 0, 0);  STAGE(gA1,  0, SA, 0, 1);
    STAGE(gB0,  0, SB, 0, 0);  STAGE(gB1,  0, SB, 0, 1);
    STAGE(gA0, 32, SA, 1, 0);  STAGE(gA1, 32, SA, 1, 1);
    STAGE(gB0, 32, SB, 1, 0);  STAGE(gB1, 32, SB, 1, 1);
    STAGE(gA0, 64, SA, 2, 0);  STAGE(gA1, 64, SA, 2, 1);
    STAGE(gB0, 64, SB, 2, 0);  STAGE(gB1, 64, SB, 2, 1);
    asm volatile("s_waitcnt vmcnt(4)" ::: "memory");   // t0 resident, t1-kh0 flying
    __builtin_amdgcn_s_barrier();
    asm volatile("" ::: "memory");

#pragma unroll 2
    for (int t = 0; t < 16; ++t) {
        const int cur = t & 1, nxt = cur ^ 1;
        const int kc = t * 64;
        const short* A0 = &SA[cur * 16384];
        const short* A1 = A0 + 8192;
        const short* B0 = &SB[cur * 16384];
        const short* B1 = B0 + 8192;

        bf16x8 af[4], bfr[4];

        // ---- P1: kh0 x mh0 (8 ds_read; stage A-kh1 of t+1 -> buf nxt) ----
#pragma unroll
        for (int i = 0; i < 4; ++i) af[i] = *(const bf16x8*)&A0[aoff[i]];
#pragma unroll
        for (int j = 0; j < 4; ++j) bfr[j] = *(const bf16x8*)&B0[boff[j]];
        if (t < 15) { STAGE(gA0, kc + 96, SA, nxt * 2 + 1, 0);
                      STAGE(gA1, kc + 96, SA, nxt * 2 + 1, 1); }
        WAIT_LGKM0();
        __builtin_amdgcn_s_setprio(1);
#pragma unroll
        for (int i = 0; i < 4; ++i)
#pragma unroll
            for (int j = 0; j < 4; ++j)
                acc[i][j] = __builtin_amdgcn_mfma_f32_16x16x32_bf16(af[i], bfr[j], acc[i][j], 0, 0, 0);
        __builtin_amdgcn_s_setprio(0);

        // ---- P2: kh0 x mh1 (4 ds_read, bfr reused; stage B-kh1 of t+1) ----
#pragma unroll
        for (int i = 0; i < 4; ++i) af[i] = *(const bf16x8*)&A0[aoff[4 + i]];
        if (t < 15) { STAGE(gB0, kc + 96, SB, nxt * 2 + 1, 0);
                      STAGE(gB1, kc + 96, SB, nxt * 2 + 1, 1); }
        WAIT_LGKM0();
        __builtin_amdgcn_s_setprio(1);
#pragma unroll
        for (int i = 0; i < 4; ++i)
#pragma unroll
            for (int j = 0; j < 4; ++j)
                acc[4 + i][j] = __builtin_amdgcn_mfma_f32_16x16x32_bf16(af[i], bfr[j], acc[4 + i][j], 0, 0, 0);
        __builtin_amdgcn_s_setprio(0);
        BARRIER();   // all waves' kh0 reads complete -> cur-kh0 stages safe

        // ---- P3: kh1 x mh0 (8 ds_read; stage A-kh0 of t+2 -> buf cur) ----
#pragma unroll
        for (int i = 0; i < 4; ++i) af[i] = *(const bf16x8*)&A1[aoff[i]];
#pragma unroll
        for (int j = 0; j < 4; ++j) bfr[j] = *(const bf16x8*)&B1[boff[j]];
        if (t < 14) { STAGE(gA0, kc + 128, SA, cur * 2, 0);
                      STAGE(gA1, kc + 128, SA, cur * 2, 1); }
        WAIT_LGKM0();
        __builtin_amdgcn_s_setprio(1);
#pragma unroll
        for (int i = 0; i < 4; ++i)
#pragma unroll
            for (int j = 0; j < 4; ++j)
                acc[i][j] = __builtin_amdgcn_mfma_f32_16x16x32_bf16(af[i], bfr[j], acc[i][j], 0, 0, 0);
        __builtin_amdgcn_s_setprio(0);

        // ---- P4: kh1 x mh1 (4 ds_read; stage B-kh0 of t+2) ----
#pragma unroll
        for (int i = 0; i < 4; ++i) af[i] = *(const bf16x8*)&A1[aoff[4 + i]];
        if (t < 14) { STAGE(gB0, kc + 128, SB, cur * 2, 0);
                      STAGE(gB1, kc + 128, SB, cur * 2, 1); }
        WAIT_LGKM0();
        __builtin_amdgcn_s_setprio(1);
#pragma unroll
        for (int i = 0; i < 4; ++i)
#pragma unroll
            for (int j = 0; j < 4; ++j)
                acc[4 + i][j] = __builtin_amdgcn_mfma_f32_16x16x32_bf16(af[i], bfr[j], acc[4 + i][j], 0, 0, 0);
        __builtin_amdgcn_s_setprio(0);
        // tile boundary: t+1's data must be resident; newest 4 loads (t+2 kh0)
        // may stay in flight. Barrier also certifies all kh1 reads complete.
        if (t <= 13) asm volatile("s_waitcnt vmcnt(4)" ::: "memory");
        else         asm volatile("s_waitcnt vmcnt(0)" ::: "memory");
        __builtin_amdgcn_s_barrier();
        asm volatile("" ::: "memory");
    }

    // ---- epilogue: p = sum over this wave's 64 e of v[e]*tanh(acc+dec+cov*wc) ----
    const int eb = n0 + wn * 64;
    float v_e[4], wc_e[4], dec_e[4];
#pragma unroll
    for (int j = 0; j < 4; ++j) {
        int e = eb + j * 16 + c;
        v_e[j]  = v_w[e];
        wc_e[j] = wc_w[e];
        float d = Wsb[e];
#pragma unroll
        for (int p = 0; p < 4; ++p) d += dec_part[(size_t)p * 131072 + (size_t)b * 1024 + e];
        dec_e[j] = d;
    }
    const float* covb = cov + (size_t)b * 512 + s0c;
    float* pp = p_part + (size_t)(bx * 4 + wn) * 65536 + (size_t)my * 256;
#pragma unroll
    for (int i = 0; i < 8; ++i)
#pragma unroll
        for (int rr = 0; rr < 4; ++rr) {
            int r = wm * 128 + i * 16 + q * 4 + rr;
            float cs = covb[r];
            float p = 0.f;
#pragma unroll
            for (int j = 0; j < 4; ++j) {
                float att = acc[i][j][rr] + dec_e[j] + cs * wc_e[j];
                p += v_e[j] * fast_tanh2(att);
            }
            p += __shfl_xor(p, 1);
            p += __shfl_xor(p, 2);
            p += __shfl_xor(p, 4);
            p += __shfl_xor(p, 8);
            if (c == 0) pp[r] = p;
        }
}

// ---------------- fallback score GEMM (fp32 A, register cvt, 16 slices) --------
__global__ __launch_bounds__(256) void attn_score_gemm_fb(
    const float* __restrict__ enc, const short* __restrict__ Wh,
    const float* __restrict__ dec_feat, const float* __restrict__ cov,
    const float* __restrict__ wc_w, const float* __restrict__ v_w,
    float* __restrict__ p_part)
{
    __shared__ __align__(16) short As[128 * 40];
    __shared__ __align__(16) short Bs[128 * 40];
    const int t = threadIdx.x;
    const int bx = blockIdx.x;
    const int by = blockIdx.y;
    const int b  = by >> 2;
    const int s0 = (by & 3) * 128;

    const int wv = t >> 6, lane = t & 63, q = lane >> 4, c = lane & 15;
    const int wm = wv & 1, wn = wv >> 1;
    const int ar = t >> 1, ah = t & 1;

    const float* aptr = enc + ((size_t)(by * 128 + ar)) * 1024 + ah * 16;
    const short* bptr = Wh + ((size_t)(bx * 128 + ar)) * 1024 + ah * 16;
    short* awr = &As[ar * 40 + ah * 16];
    short* bwr = &Bs[ar * 40 + ah * 16];

    f32x4 acc[4][4];
#pragma unroll
    for (int i = 0; i < 4; ++i)
#pragma unroll
        for (int j = 0; j < 4; ++j) acc[i][j] = (f32x4){0.f, 0.f, 0.f, 0.f};

    for (int k0 = 0; k0 < 1024; k0 += 32) {
        const float4* ap = (const float4*)(aptr + k0);
        float4 a0 = ap[0], a1 = ap[1], a2 = ap[2], a3 = ap[3];
        bf16x8 bv0 = *(const bf16x8*)(bptr + k0);
        bf16x8 bv1 = *(const bf16x8*)(bptr + k0 + 8);
        *(bf16x8*)awr = cvt8(a0, a1);
        *(bf16x8*)(awr + 8) = cvt8(a2, a3);
        *(bf16x8*)bwr = bv0;
        *(bf16x8*)(bwr + 8) = bv1;
        __syncthreads();
        bf16x8 af[4], bf[4];
#pragma unroll
        for (int i = 0; i < 4; ++i) af[i] = *(const bf16x8*)&As[(wm * 64 + i * 16 + c) * 40 + q * 8];
#pragma unroll
        for (int j = 0; j < 4; ++j) bf[j] = *(const bf16x8*)&Bs[(wn * 64 + j * 16 + c) * 40 + q * 8];
#pragma unroll
        for (int i = 0; i < 4; ++i)
#pragma unroll
            for (int j = 0; j < 4; ++j)
                acc[i][j] = __builtin_amdgcn_mfma_f32_16x16x32_bf16(af[i], bf[j], acc[i][j], 0, 0, 0);
        __syncthreads();
    }

    const int n0 = bx * 128 + wn * 64;
    float v_e[4], wc_e[4], dec_e[4];
#pragma unroll
    for (int j = 0; j < 4; ++j) {
        int e = n0 + j * 16 + c;
        v_e[j]  = v_w[e];
        wc_e[j] = wc_w[e];
        dec_e[j] = dec_feat[(size_t)b * 1024 + e];
    }
    const float* covb = cov + (size_t)b * 512;
    float* pp = p_part + ((size_t)(bx * 2 + wn)) * 65536 + (size_t)b * 512;
#pragma unroll
    for (int i = 0; i < 4; ++i)
#pragma unroll
        for (int rr = 0; rr < 4; ++rr) {
            int s = s0 + wm * 64 + i * 16 + q * 4 + rr;
            float cs = covb[s];
            float p = 0.f;
#pragma unroll
            for (int j = 0; j < 4; ++j) {
                float att = acc[i][j][rr] + dec_e[j] + cs * wc_e[j];
                p += v_e[j] * fast_tanh(att);
            }
            p += __shfl_xor(p, 1);
            p += __shfl_xor(p, 2);
            p += __shfl_xor(p, 4);
            p += __shfl_xor(p, 8);
            if (c == 0) pp[s] = p;
        }
}

// fallback dec gemm (bf16 Ws, full K, with bias)
__global__ __launch_bounds__(256) void dec_gemm(
    const float* __restrict__ hd, const float* __restrict__ cd,
    const short* __restrict__ Ws, const float* __restrict__ Wsb,
    float* __restrict__ dec_feat)
{
    __shared__ __align__(16) short As[128 * 40];
    __shared__ __align__(16) short Bs[128 * 40];
    const int t = threadIdx.x;
    const int bx = blockIdx.x;
    const int wv = t >> 6, lane = t & 63, q = lane >> 4, c = lane & 15;
    const int wm = wv & 1, wn = wv >> 1;
    const int ar = t >> 1, ah = t & 1;

    const short* bptr = Ws + ((size_t)(bx * 128 + ar)) * 1024 + ah * 16;
    short* awr = &As[ar * 40 + ah * 16];
    short* bwr = &Bs[ar * 40 + ah * 16];

    f32x4 acc[4][4];
#pragma unroll
    for (int i = 0; i < 4; ++i)
#pragma unroll
        for (int j = 0; j < 4; ++j) acc[i][j] = (f32x4){0.f, 0.f, 0.f, 0.f};

    for (int k0 = 0; k0 < 1024; k0 += 32) {
        const int k = k0 + ah * 16;
        const float* src = (k < 512) ? (hd + (size_t)ar * 512 + k)
                                     : (cd + (size_t)ar * 512 + (k - 512));
        const float4* ap = (const float4*)src;
        float4 a0 = ap[0], a1 = ap[1], a2 = ap[2], a3 = ap[3];
        bf16x8 bv0 = *(const bf16x8*)(bptr + k0);
        bf16x8 bv1 = *(const bf16x8*)(bptr + k0 + 8);
        *(bf16x8*)awr = cvt8(a0, a1);
        *(bf16x8*)(awr + 8) = cvt8(a2, a3);
        *(bf16x8*)bwr = bv0;
        *(bf16x8*)(bwr + 8) = bv1;
        __syncthreads();
        bf16x8 af[4], bf[4];
#pragma unroll
        for (int i = 0; i < 4; ++i) af[i] = *(const bf16x8*)&As[(wm * 64 + i * 16 + c) * 40 + q * 8];
#pragma unroll
        for (int j = 0; j < 4; ++j) bf[j] = *(const bf16x8*)&Bs[(wn * 64 + j * 16 + c) * 40 + q * 8];
#pragma unroll
        for (int i = 0; i < 4; ++i)
#pragma unroll
            for (int j = 0; j < 4; ++j)
                acc[i][j] = __builtin_amdgcn_mfma_f32_16x16x32_bf16(af[i], bf[j], acc[i][j], 0, 0, 0);
        __syncthreads();
    }

    const int n0 = bx * 128 + wn * 64;
    float wsb_e[4];
#pragma unroll
    for (int j = 0; j < 4; ++j) wsb_e[j] = Wsb[n0 + j * 16 + c];
#pragma unroll
    for (int i = 0; i < 4; ++i)
#pragma unroll
        for (int rr = 0; rr < 4; ++rr) {
            int bidx = wm * 64 + i * 16 + q * 4 + rr;
#pragma unroll
            for (int j = 0; j < 4; ++j) {
                int e = n0 + j * 16 + c;
                dec_feat[(size_t)bidx * 1024 + e] = acc[i][j][rr] + wsb_e[j];
            }
        }
}

// ---------------- softmax: sum ns partials, masked softmax + renorm ------------
__global__ __launch_bounds__(512) void softmax_kernel(
    const float* __restrict__ p_part, int ns, const float* __restrict__ mask,
    const float* __restrict__ cov, float* __restrict__ aw, float* __restrict__ ncov)
{
    __shared__ float red[8];
    const int b = blockIdx.x, t = threadIdx.x;
    const int w = t >> 6, lane = t & 63;
    const size_t idx = (size_t)b * 512 + t;

    float sc = 0.f;
    for (int k = 0; k < ns; ++k) sc += p_part[(size_t)k * 65536 + idx];

    float m = sc;
#pragma unroll
    for (int o = 1; o < 64; o <<= 1) m = fmaxf(m, __shfl_xor(m, o));
    if (lane == 0) red[w] = m;
    __syncthreads();
#pragma unroll
    for (int i = 0; i < 8; ++i) m = fmaxf(m, red[i]);
    __syncthreads();

    float e = __expf(sc - m);
    float s = e;
#pragma unroll
    for (int o = 1; o < 64; o <<= 1) s += __shfl_xor(s, o);
    if (lane == 0) red[w] = s;
    __syncthreads();
    s = 0.f;
#pragma unroll
    for (int i = 0; i < 8; ++i) s += red[i];
    __syncthreads();

    float wv = (e / s) * mask[idx];
    float s2 = wv;
#pragma unroll
    for (int o = 1; o < 64; o <<= 1) s2 += __shfl_xor(s2, o);
    if (lane == 0) red[w] = s2;
    __syncthreads();
    s2 = 0.f;
#pragma unroll
    for (int i = 0; i < 8; ++i) s2 += red[i];

    float awv = wv / s2;
    aw[idx] = awv;
    ncov[idx] = cov[idx] + awv;
}

// ---------------- context: partial-sum (no atomics) + reduce -------------------
__global__ __launch_bounds__(256) void context_part(
    const short* __restrict__ encb, const float* __restrict__ aw, float* __restrict__ cpart)
{
    const int sc = blockIdx.x & 7;     // s-chunk of 64
    const int b  = blockIdx.x >> 3;    // 0..127
    const int t  = threadIdx.x;
    const int dl = t & 127;
    const int si = t >> 7;
    const short* ebase = encb + ((size_t)(b * 512 + sc * 64 + si)) * 1024 + dl * 8;
    const float* awp = aw + (size_t)b * 512 + sc * 64 + si;
    float acc[8];
#pragma unroll
    for (int i = 0; i < 8; ++i) acc[i] = 0.f;
#pragma unroll 16
    for (int s = 0; s < 64; s += 2) {
        float w = awp[s];
        bf16x8 e = *(const bf16x8*)(ebase + (size_t)s * 1024);
#pragma unroll
        for (int i = 0; i < 8; ++i) acc[i] += w * bf2f(e[i]);
    }
    float* cp = cpart + ((size_t)(sc * 2 + si) * 128 + b) * 1024 + dl * 8;
    *(float4*)(cp)     = (float4){acc[0], acc[1], acc[2], acc[3]};
    *(float4*)(cp + 4) = (float4){acc[4], acc[5], acc[6], acc[7]};
}

__global__ __launch_bounds__(256) void ctx_reduce(
    const float* __restrict__ cpart, float* __restrict__ ctx)
{
    int i = blockIdx.x * 256 + threadIdx.x;
    float s = 0.f;
#pragma unroll
    for (int k = 0; k < 16; ++k) s += cpart[(size_t)k * 131072 + i];
    ctx[i] = s;
}

// fp32 fallback context
__global__ __launch_bounds__(256) void context_f32(
    const float* __restrict__ enc, const float* __restrict__ aw, float* __restrict__ ctx)
{
    const int schunk = blockIdx.x;
    const int b = blockIdx.y;
    const int t = threadIdx.x;
    const float* ebase = enc + ((size_t)(b * 512 + schunk * 128)) * 1024 + t * 4;
    const float* awp = aw + (size_t)b * 512 + schunk * 128;
    float ax = 0.f, ay = 0.f, az = 0.f, aww = 0.f;
#pragma unroll 4
    for (int s = 0; s < 128; ++s) {
        float w = awp[s];
        float4 e4 = *(const float4*)(ebase + (size_t)s * 1024);
        ax += w * e4.x; ay += w * e4.y; az += w * e4.z; aww += w * e4.w;
    }
    float* cp = ctx + (size_t)b * 1024 + t * 4;
    atomicAdd(cp + 0, ax);
    atomicAdd(cp + 1, ay);
    atomicAdd(cp + 2, az);
    atomicAdd(cp + 3, aww);
}

// small cvt for fallback path (weights only)
__global__ void cvt_f32_bf16(const float* __restrict__ src, short* __restrict__ dst, int n) {
    int i = (blockIdx.x * 256 + threadIdx.x) * 4;
    if (i < n) {
        float4 f = *(const float4*)(src + i);
        short4 o;
        o.x = f2bf(f.x); o.y = f2bf(f.y); o.z = f2bf(f.z); o.w = f2bf(f.w);
        *(short4*)(dst + i) = o;
    }
}

extern "C" void kernel_launch(void* const* d_in, const int* in_sizes, int n_in,
                              void* d_out, int out_size, void* d_ws, size_t ws_size,
                              hipStream_t stream) {
    const float* hd   = (const float*)d_in[0];
    const float* cd   = (const float*)d_in[1];
    const float* enc  = (const float*)d_in[2];
    const float* mask = (const float*)d_in[3];
    const float* cov  = (const float*)d_in[4];
    const float* Wh   = (const float*)d_in[5];
    const float* Ws   = (const float*)d_in[6];
    const float* Wsb  = (const float*)d_in[7];
    const float* vw   = (const float*)d_in[8];
    const float* wcw  = (const float*)d_in[9];

    float* out  = (float*)d_out;
    float* ctx  = out;
    float* aw   = out + 131072;
    float* ncov = out + 196608;

    // ws layout (big path): p_part 4MB | dec_part 2MB | Wh_bf 2MB | enc_bf 128MB
    // cpart (8MB) overlays [0..8MB) — all dead by context time.
    char* ws = (char*)d_ws;
    float* p_part   = (float*)ws;
    float* dec_part = (float*)(ws + (4u << 20));
    short* Wh_bf    = (short*)(ws + (6u << 20));
    short* enc_bf   = (short*)(ws + (8u << 20));
    float* cpart    = (float*)ws;
    const size_t need_big = (8ull << 20) + (128ull << 20);

    if (ws_size >= need_big) {
        cvt_plus_dec<<<33312, 256, 0, stream>>>(enc, Wh, enc_bf, Wh_bf, hd, cd, Ws, dec_part);
        attn_score_gemm8<<<1024, 512, 0, stream>>>(enc_bf, Wh_bf, dec_part, Wsb, cov, wcw, vw, p_part);
        softmax_kernel<<<128, 512, 0, stream>>>(p_part, 16, mask, cov, aw, ncov);
        context_part<<<1024, 256, 0, stream>>>(enc_bf, aw, cpart);
        ctx_reduce<<<512, 256, 0, stream>>>(cpart, ctx);
    } else {
        // fallback layout: p_part 4MB | dec_feat 512KB | Wh_bf 2MB | Ws_bf 2MB
        float* p_part16 = (float*)ws;
        float* dec_feat = (float*)(ws + (4u << 20));
        short* Wh_bf2   = (short*)(ws + (4u << 20) + (512u << 10));
        short* Ws_bf    = (short*)(ws + (6u << 20) + (512u << 10));
        hipMemsetAsync(ctx, 0, 128 * 1024 * sizeof(float), stream);
        cvt_f32_bf16<<<1024, 256, 0, stream>>>(Wh, Wh_bf2, 1024 * 1024);
        cvt_f32_bf16<<<1024, 256, 0, stream>>>(Ws, Ws_bf, 1024 * 1024);
        dec_gemm<<<8, 256, 0, stream>>>(hd, cd, Ws_bf, Wsb, dec_feat);
        attn_score_gemm_fb<<<dim3(8, 512), 256, 0, stream>>>(enc, Wh_bf2, dec_feat, cov, wcw, vw, p_part16);
        softmax_kernel<<<128, 512, 0, stream>>>(p_part16, 16, mask, cov, aw, ncov);
        context_f32<<<dim3(4, 128), 256, 0, stream>>>(enc, aw, ctx);
    }
}